// Round 1
// baseline (2136.337 us; speedup 1.0000x reference)
//
#include <hip/hip_runtime.h>
#include <math.h>

// Fixed problem dims
constexpr int kB  = 4;
constexpr int kD  = 256;
constexpr int kNQ = 4096;
constexpr int kNK = 4096;
constexpr int kHW = 4096;   // 64*64

// ---------------------------------------------------------------- fold w1
// w1eff[h][d] = w1[h][d] + w1[h][d+256]   (w1 is [256][512])
__global__ void k_fold_w1(const float* __restrict__ w1, float* __restrict__ w1e) {
    int h = blockIdx.x, d = threadIdx.x;
    w1e[h * 256 + d] = w1[h * 512 + d] + w1[h * 512 + 256 + d];
}

// ------------------------------------------------- C = act(A @ W^T + bias)
// A [M,256] row-major, W [256,256] row-major ([n][k]), C [M,256].
// grid = (M/64)*4, block = 256. 64x64 tile, 4x4 per thread.
__global__ __launch_bounds__(256) void k_gemm_awt(
    const float* __restrict__ A, const float* __restrict__ W,
    const float* __restrict__ bias, float* __restrict__ C, int relu)
{
    __shared__ float As[64][36];   // 144B rows: float4-aligned, <=2-way banks
    __shared__ float Ws[64][36];
    const int t  = threadIdx.x;
    const int m0 = (blockIdx.x >> 2) * 64;
    const int n0 = (blockIdx.x & 3) * 64;
    const int tx = t & 15, ty = t >> 4;
    const int lr = t >> 3, lc = (t & 7) << 2;
    float acc[4][4] = {};
    for (int kt = 0; kt < 8; ++kt) {
        const int k0 = kt * 32;
        #pragma unroll
        for (int it = 0; it < 2; ++it) {
            const int r = lr + it * 32;
            *(float4*)&As[r][lc] = *(const float4*)&A[(size_t)(m0 + r) * 256 + k0 + lc];
            *(float4*)&Ws[r][lc] = *(const float4*)&W[(size_t)(n0 + r) * 256 + k0 + lc];
        }
        __syncthreads();
        #pragma unroll
        for (int k4 = 0; k4 < 8; ++k4) {
            float4 a[4], bv[4];
            #pragma unroll
            for (int i = 0; i < 4; ++i) a[i]  = *(const float4*)&As[ty * 4 + i][k4 * 4];
            #pragma unroll
            for (int j = 0; j < 4; ++j) bv[j] = *(const float4*)&Ws[tx + 16 * j][k4 * 4];
            #pragma unroll
            for (int i = 0; i < 4; ++i)
                #pragma unroll
                for (int j = 0; j < 4; ++j)
                    acc[i][j] += a[i].x * bv[j].x + a[i].y * bv[j].y
                               + a[i].z * bv[j].z + a[i].w * bv[j].w;
        }
        __syncthreads();
    }
    #pragma unroll
    for (int i = 0; i < 4; ++i) {
        const int m = m0 + ty * 4 + i;
        #pragma unroll
        for (int j = 0; j < 4; ++j) {
            const int n = n0 + tx + 16 * j;
            float v = acc[i][j];
            if (bias) v += bias[n];
            if (relu) v = fmaxf(v, 0.f);
            C[(size_t)m * 256 + n] = v;
        }
    }
}

// ---------------------------------------------------------------- L2 norm
// One wave per 256-elem row; in==out allowed (row-local).
__global__ __launch_bounds__(256) void k_l2norm(const float* __restrict__ in,
                                                float* __restrict__ out) {
    const int row  = blockIdx.x * 4 + (threadIdx.x >> 6);
    const int lane = threadIdx.x & 63;
    float4 v = ((const float4*)(in + (size_t)row * 256))[lane];
    float ss = v.x * v.x + v.y * v.y + v.z * v.z + v.w * v.w;
    #pragma unroll
    for (int off = 32; off; off >>= 1) ss += __shfl_xor(ss, off, 64);
    const float rn = 1.0f / sqrtf(ss);
    float4 o; o.x = v.x * rn; o.y = v.y * rn; o.z = v.z * rn; o.w = v.w * rn;
    ((float4*)(out + (size_t)row * 256))[lane] = o;
}

// ---------------------------------------------------------------- attention
// out_fm[b][d][q] = sum_k relu(qn[b,q,:]·kn[b,k,:]) * ow[b,k] * vp[b,k,d]
// grid = B*128 (32-row q tiles), block = 256 (4 waves).
__global__ __launch_bounds__(256) void k_attn(
    const float* __restrict__ qn, const float* __restrict__ kn,
    const float* __restrict__ vp, const float* __restrict__ ow,
    float* __restrict__ out_fm)
{
    __shared__ float smem[32 * 260 * 2 + 32 * 36];   // 71168 B
    float* qs = smem;              // [32][260]
    float* ks = smem + 32 * 260;   // [32][260]
    float* ps = smem + 64 * 260;   // [32][36], stored [kk][qq]
    const int t  = threadIdx.x;
    const int b  = blockIdx.x >> 7;
    const int q0 = (blockIdx.x & 127) << 5;
    // load q tile (32 x 256)
    #pragma unroll
    for (int i = 0; i < 8; ++i) {
        const int idx = t + (i << 8);
        const int r = idx >> 6, c = (idx & 63) << 2;
        *(float4*)&qs[r * 260 + c] =
            *(const float4*)&qn[((size_t)b * kNQ + q0 + r) * kD + c];
    }
    const int tq = t >> 4, tk = t & 15;      // QK: 2q x 2k per thread
    const int wv = t >> 6, lane = t & 63;    // PV: wave-split over q
    float acc[8][4] = {};
    for (int kt = 0; kt < 128; ++kt) {
        const int k0 = kt << 5;
        __syncthreads();   // previous PV done before ks/ps overwrite
        #pragma unroll
        for (int i = 0; i < 8; ++i) {
            const int idx = t + (i << 8);
            const int r = idx >> 6, c = (idx & 63) << 2;
            *(float4*)&ks[r * 260 + c] =
                *(const float4*)&kn[((size_t)b * kNK + k0 + r) * kD + c];
        }
        __syncthreads();
        // ---- QK^T 2x2
        float s00 = 0.f, s01 = 0.f, s10 = 0.f, s11 = 0.f;
        const float* qa = &qs[(2 * tq) * 260];
        const float* qb = &qs[(2 * tq + 1) * 260];
        const float* ka = &ks[tk * 260];
        const float* kb = &ks[(tk + 16) * 260];
        #pragma unroll 8
        for (int d4 = 0; d4 < 64; ++d4) {
            const float4 a0 = *(const float4*)&qa[d4 * 4];
            const float4 a1 = *(const float4*)&qb[d4 * 4];
            const float4 b0 = *(const float4*)&ka[d4 * 4];
            const float4 b1 = *(const float4*)&kb[d4 * 4];
            s00 += a0.x * b0.x + a0.y * b0.y + a0.z * b0.z + a0.w * b0.w;
            s01 += a0.x * b1.x + a0.y * b1.y + a0.z * b1.z + a0.w * b1.w;
            s10 += a1.x * b0.x + a1.y * b0.y + a1.z * b0.z + a1.w * b0.w;
            s11 += a1.x * b1.x + a1.y * b1.y + a1.z * b1.z + a1.w * b1.w;
        }
        const float w0  = ow[b * kNK + k0 + tk];
        const float w1v = ow[b * kNK + k0 + tk + 16];
        ps[tk * 36 + 2 * tq]            = fmaxf(s00, 0.f) * w0;
        ps[(tk + 16) * 36 + 2 * tq]     = fmaxf(s01, 0.f) * w1v;
        ps[tk * 36 + 2 * tq + 1]        = fmaxf(s10, 0.f) * w0;
        ps[(tk + 16) * 36 + 2 * tq + 1] = fmaxf(s11, 0.f) * w1v;
        __syncthreads();
        // ---- PV: wave wv owns q rows 8*wv..8*wv+7, lane owns d = 4*lane..+3
        const float* vbase = &vp[((size_t)b * kNK + k0) * kD + lane * 4];
        #pragma unroll 4
        for (int kk = 0; kk < 32; ++kk) {
            const float4 vv = *(const float4*)&vbase[(size_t)kk * kD];
            const float4 p0 = *(const float4*)&ps[kk * 36 + 8 * wv];
            const float4 p1 = *(const float4*)&ps[kk * 36 + 8 * wv + 4];
            const float pv[8] = {p0.x, p0.y, p0.z, p0.w, p1.x, p1.y, p1.z, p1.w};
            #pragma unroll
            for (int i = 0; i < 8; ++i) {
                acc[i][0] += pv[i] * vv.x; acc[i][1] += pv[i] * vv.y;
                acc[i][2] += pv[i] * vv.z; acc[i][3] += pv[i] * vv.w;
            }
        }
    }
    // ---- transpose through LDS, write [b][d][q] coalesced
    __syncthreads();
    float* tr = smem;   // [256][33] = 8448 floats, fits
    #pragma unroll
    for (int i = 0; i < 8; ++i)
        #pragma unroll
        for (int c = 0; c < 4; ++c)
            tr[(lane * 4 + c) * 33 + 8 * wv + i] = acc[i][c];
    __syncthreads();
    #pragma unroll
    for (int j = 0; j < 32; ++j) {
        const int d  = (t >> 5) + 8 * j;
        const int qq = t & 31;
        out_fm[((size_t)b * kD + d) * kNQ + q0 + qq] = tr[d * 33 + qq];
    }
}

// -------------------------------------------- conv3x3 (SAME) + BN + SiLU
// in [B][256][64][64], cw [256][256][3][3]. grid = B*64 (4 co per block).
__global__ __launch_bounds__(256) void k_conv3_bn_silu(
    const float* __restrict__ in, const float* __restrict__ cw,
    const float* __restrict__ bn_g, const float* __restrict__ bn_b,
    const float* __restrict__ bn_m, const float* __restrict__ bn_v,
    float* __restrict__ out)
{
    __shared__ float plane[4096];
    const int t   = threadIdx.x;
    const int b   = blockIdx.x >> 6;
    const int co0 = (blockIdx.x & 63) << 2;
    const int w   = t & 63;
    const int hb  = (t >> 6) << 4;   // wave owns 16 consecutive rows
    const float* inb = in + (size_t)b * kD * kHW;
    float acc[4][16];
    #pragma unroll
    for (int c = 0; c < 4; ++c)
        #pragma unroll
        for (int j = 0; j < 16; ++j) acc[c][j] = 0.f;
    float4 pf[4];
    #pragma unroll
    for (int j = 0; j < 4; ++j)
        pf[j] = *(const float4*)&inb[(size_t)(t + 256 * j) * 4];
    for (int ci = 0; ci < 256; ++ci) {
        #pragma unroll
        for (int j = 0; j < 4; ++j)
            *(float4*)&plane[(t + 256 * j) * 4] = pf[j];
        __syncthreads();
        if (ci + 1 < 256) {   // prefetch next plane under compute
            #pragma unroll
            for (int j = 0; j < 4; ++j)
                pf[j] = *(const float4*)&inb[(size_t)(ci + 1) * kHW + (t + 256 * j) * 4];
        }
        float w9[4][9];   // uniform -> scalar loads
        #pragma unroll
        for (int c = 0; c < 4; ++c)
            #pragma unroll
            for (int k = 0; k < 9; ++k)
                w9[c][k] = cw[((size_t)(co0 + c) * 256 + ci) * 9 + k];
        float r00, r01, r02, r10, r11, r12, r20, r21, r22;
        if (hb > 0) {
            const float* row = &plane[(hb - 1) * 64];
            r00 = (w > 0) ? row[w - 1] : 0.f; r01 = row[w];
            r02 = (w < 63) ? row[w + 1] : 0.f;
        } else { r00 = r01 = r02 = 0.f; }
        {
            const float* row = &plane[hb * 64];
            r10 = (w > 0) ? row[w - 1] : 0.f; r11 = row[w];
            r12 = (w < 63) ? row[w + 1] : 0.f;
        }
        #pragma unroll
        for (int hh = 0; hh < 16; ++hh) {
            const int h2 = hb + hh + 1;
            if (h2 <= 63) {
                const float* row = &plane[h2 * 64];
                r20 = (w > 0) ? row[w - 1] : 0.f; r21 = row[w];
                r22 = (w < 63) ? row[w + 1] : 0.f;
            } else { r20 = r21 = r22 = 0.f; }
            #pragma unroll
            for (int c = 0; c < 4; ++c)
                acc[c][hh] += r00 * w9[c][0] + r01 * w9[c][1] + r02 * w9[c][2]
                            + r10 * w9[c][3] + r11 * w9[c][4] + r12 * w9[c][5]
                            + r20 * w9[c][6] + r21 * w9[c][7] + r22 * w9[c][8];
            r00 = r10; r01 = r11; r02 = r12;
            r10 = r20; r11 = r21; r12 = r22;
        }
        __syncthreads();
    }
    #pragma unroll
    for (int c = 0; c < 4; ++c) {
        const int co = co0 + c;
        const float inv = bn_g[co] / sqrtf(bn_v[co] + 1e-3f);
        const float add = bn_b[co] - bn_m[co] * inv;
        #pragma unroll
        for (int hh = 0; hh < 16; ++hh) {
            const float x = acc[c][hh] * inv + add;
            const float s = x / (1.f + expf(-x));   // SiLU
            out[((size_t)b * kD + co) * kHW + (hb + hh) * 64 + w] = s;
        }
    }
}

// ----------------------------------- conv1x1 + bias + residual (out = q + ...)
// X [B][256][4096], W2 [256][256]. grid = B*4*64, block 256.
__global__ __launch_bounds__(256) void k_conv1x1_res(
    const float* __restrict__ X, const float* __restrict__ W2,
    const float* __restrict__ bias2, const float* __restrict__ query,
    float* __restrict__ out)
{
    __shared__ float As[64][36];
    __shared__ float Xs[32][68];   // 272B rows: float4-aligned
    const int t   = threadIdx.x;
    const int b   = blockIdx.x >> 8;
    const int rem = blockIdx.x & 255;
    const int co0 = (rem >> 6) << 6;
    const int hw0 = (rem & 63) << 6;
    const int tx  = t & 15, ty = t >> 4;
    const float* Xb = X + (size_t)b * kD * kHW;
    float acc[4][4] = {};
    for (int kt = 0; kt < 8; ++kt) {
        const int k0 = kt * 32;
        {
            const int lr = t >> 3, lc = (t & 7) << 2;
            #pragma unroll
            for (int it = 0; it < 2; ++it) {
                const int r = lr + it * 32;
                *(float4*)&As[r][lc] =
                    *(const float4*)&W2[(size_t)(co0 + r) * 256 + k0 + lc];
            }
        }
        #pragma unroll
        for (int i = 0; i < 2; ++i) {
            const int idx = t + 256 * i;        // float4 units
            const int r = idx >> 4, c4 = (idx & 15) << 2;
            *(float4*)&Xs[r][c4] =
                *(const float4*)&Xb[(size_t)(k0 + r) * kHW + hw0 + c4];
        }
        __syncthreads();
        #pragma unroll
        for (int k4 = 0; k4 < 8; ++k4) {
            float4 a[4];
            #pragma unroll
            for (int i = 0; i < 4; ++i) a[i] = *(const float4*)&As[ty * 4 + i][k4 * 4];
            #pragma unroll
            for (int kk = 0; kk < 4; ++kk) {
                const float4 x = *(const float4*)&Xs[k4 * 4 + kk][tx * 4];
                #pragma unroll
                for (int i = 0; i < 4; ++i) {
                    const float av = ((const float*)&a[i])[kk];
                    acc[i][0] += av * x.x; acc[i][1] += av * x.y;
                    acc[i][2] += av * x.z; acc[i][3] += av * x.w;
                }
            }
        }
        __syncthreads();
    }
    #pragma unroll
    for (int i = 0; i < 4; ++i) {
        const int co = co0 + ty * 4 + i;
        const float bb = bias2[co];
        const size_t base = ((size_t)b * kD + co) * kHW + hw0 + tx * 4;
        const float4 q4 = *(const float4*)&query[base];
        float4 o;
        o.x = acc[i][0] + bb + q4.x; o.y = acc[i][1] + bb + q4.y;
        o.z = acc[i][2] + bb + q4.z; o.w = acc[i][3] + bb + q4.w;
        *(float4*)&out[base] = o;
    }
}

// ---------------------------------------------------------------- launch
extern "C" void kernel_launch(void* const* d_in, const int* in_sizes, int n_in,
                              void* d_out, int out_size, void* d_ws, size_t ws_size,
                              hipStream_t stream) {
    const float* query   = (const float*)d_in[0];
    const float* v_in    = (const float*)d_in[1];
    const float* qpos    = (const float*)d_in[2];
    const float* kpos    = (const float*)d_in[3];
    const float* otherW  = (const float*)d_in[4];
    const float* w_vs    = (const float*)d_in[5];
    const float* mlp_w1  = (const float*)d_in[6];
    const float* mlp_b1  = (const float*)d_in[7];
    const float* mlp_w2  = (const float*)d_in[8];
    const float* mlp_b2  = (const float*)d_in[9];
    const float* conv1_w = (const float*)d_in[10];
    const float* bn_g    = (const float*)d_in[11];
    const float* bn_b    = (const float*)d_in[12];
    const float* bn_m    = (const float*)d_in[13];
    const float* bn_v    = (const float*)d_in[14];
    const float* conv2_w = (const float*)d_in[15];
    const float* conv2_b = (const float*)d_in[16];
    float* out = (float*)d_out;
    float* ws  = (float*)d_ws;

    constexpr size_t BUF = (size_t)kB * kNQ * kD;   // 4194304 floats
    float* vproj = ws;            // [B][NK][D]
    float* qn    = ws + BUF;      // [B][NQ][D]
    float* kn    = ws + 2 * BUF;  // [B][NK][D]
    float* w1e   = ws + 3 * BUF;  // [256][256]
    float* qhid    = out;         // d_out doubles as scratch (fully overwritten later)
    float* attn_fm = out;
    float* silu    = vproj;       // vproj free after attention

    k_fold_w1<<<256, 256, 0, stream>>>(mlp_w1, w1e);
    k_gemm_awt<<<1024, 256, 0, stream>>>(v_in, w_vs, nullptr, vproj, 0);
    k_gemm_awt<<<1024, 256, 0, stream>>>(qpos, w1e, mlp_b1, qhid, 1);
    k_gemm_awt<<<1024, 256, 0, stream>>>(qhid, mlp_w2, mlp_b2, qn, 0);
    k_l2norm<<<4096, 256, 0, stream>>>(qn, qn);
    k_l2norm<<<4096, 256, 0, stream>>>(kpos, kn);
    k_attn<<<512, 256, 0, stream>>>(qn, kn, vproj, otherW, attn_fm);
    k_conv3_bn_silu<<<256, 256, 0, stream>>>(attn_fm, conv1_w, bn_g, bn_b, bn_m, bn_v, silu);
    k_conv1x1_res<<<1024, 256, 0, stream>>>(silu, conv2_w, conv2_b, query, out);
}

// Round 2
// 1200.841 us; speedup vs baseline: 1.7790x; 1.7790x over previous
//
#include <hip/hip_runtime.h>
#include <math.h>

// Fixed problem dims
constexpr int kB  = 4;
constexpr int kD  = 256;
constexpr int kNQ = 4096;
constexpr int kNK = 4096;
constexpr int kHW = 4096;   // 64*64

typedef __bf16 bf16x8 __attribute__((ext_vector_type(8)));
typedef float  f32x16 __attribute__((ext_vector_type(16)));

__device__ __forceinline__ unsigned short f2bf(float x) {
    unsigned int u = __builtin_bit_cast(unsigned int, x);
    u = (u + 0x7fffu + ((u >> 16) & 1u)) >> 16;
    return (unsigned short)u;
}

// ---------------------------------------------------------------- fold w1
__global__ void k_fold_w1(const float* __restrict__ w1, float* __restrict__ w1e) {
    int h = blockIdx.x, d = threadIdx.x;
    w1e[h * 256 + d] = w1[h * 512 + d] + w1[h * 512 + 256 + d];
}

// ------------------------------------------------- C = act(A @ W^T + bias)  (fp32)
__global__ __launch_bounds__(256) void k_gemm_awt(
    const float* __restrict__ A, const float* __restrict__ W,
    const float* __restrict__ bias, float* __restrict__ C, int relu)
{
    __shared__ float As[64][36];
    __shared__ float Ws[64][36];
    const int t  = threadIdx.x;
    const int m0 = (blockIdx.x >> 2) * 64;
    const int n0 = (blockIdx.x & 3) * 64;
    const int tx = t & 15, ty = t >> 4;
    const int lr = t >> 3, lc = (t & 7) << 2;
    float acc[4][4] = {};
    for (int kt = 0; kt < 8; ++kt) {
        const int k0 = kt * 32;
        #pragma unroll
        for (int it = 0; it < 2; ++it) {
            const int r = lr + it * 32;
            *(float4*)&As[r][lc] = *(const float4*)&A[(size_t)(m0 + r) * 256 + k0 + lc];
            *(float4*)&Ws[r][lc] = *(const float4*)&W[(size_t)(n0 + r) * 256 + k0 + lc];
        }
        __syncthreads();
        #pragma unroll
        for (int k4 = 0; k4 < 8; ++k4) {
            float4 a[4], bv[4];
            #pragma unroll
            for (int i = 0; i < 4; ++i) a[i]  = *(const float4*)&As[ty * 4 + i][k4 * 4];
            #pragma unroll
            for (int j = 0; j < 4; ++j) bv[j] = *(const float4*)&Ws[tx + 16 * j][k4 * 4];
            #pragma unroll
            for (int i = 0; i < 4; ++i)
                #pragma unroll
                for (int j = 0; j < 4; ++j)
                    acc[i][j] += a[i].x * bv[j].x + a[i].y * bv[j].y
                               + a[i].z * bv[j].z + a[i].w * bv[j].w;
        }
        __syncthreads();
    }
    #pragma unroll
    for (int i = 0; i < 4; ++i) {
        const int m = m0 + ty * 4 + i;
        #pragma unroll
        for (int j = 0; j < 4; ++j) {
            const int n = n0 + tx + 16 * j;
            float v = acc[i][j];
            if (bias) v += bias[n];
            if (relu) v = fmaxf(v, 0.f);
            C[(size_t)m * 256 + n] = v;
        }
    }
}

// -------------------------------------------- transpose + f32->bf16 convert
// in [B][4096][256] f32 -> out [B][256][4096] bf16. 64x64 tiles.
__global__ __launch_bounds__(256) void k_transpose_cvt(
    const float* __restrict__ in, ushort* __restrict__ out)
{
    __shared__ ushort trs[64][72];   // 144B rows, 16B-aligned
    const int bid = blockIdx.x;
    const int b = bid >> 8, dt = (bid >> 6) & 3, kt = bid & 63;
    const int d0 = dt * 64, k0 = kt * 64;
    const int t = threadIdx.x;
    const int kl = t >> 4, d4 = (t & 15) * 4;
    #pragma unroll
    for (int it = 0; it < 4; ++it) {
        const int k = kl + it * 16;
        float4 v = *(const float4*)&in[((size_t)b * kNK + k0 + k) * kD + d0 + d4];
        trs[d4 + 0][k] = f2bf(v.x); trs[d4 + 1][k] = f2bf(v.y);
        trs[d4 + 2][k] = f2bf(v.z); trs[d4 + 3][k] = f2bf(v.w);
    }
    __syncthreads();
    const int dl = t >> 2, c0 = (t & 3) * 16;
    uint4 a  = *(uint4*)&trs[dl][c0];
    uint4 bb = *(uint4*)&trs[dl][c0 + 8];
    const size_t ob = ((size_t)b * kD + d0 + dl) * (size_t)kNK + k0 + c0;
    *(uint4*)&out[ob]     = a;
    *(uint4*)&out[ob + 8] = bb;
}

// ---------------------------------------------------------------- L2 norm -> bf16
__global__ __launch_bounds__(256) void k_l2norm_bf16(const float* __restrict__ in,
                                                     ushort* __restrict__ out) {
    const int row  = blockIdx.x * 4 + (threadIdx.x >> 6);
    const int lane = threadIdx.x & 63;
    float4 v = ((const float4*)(in + (size_t)row * 256))[lane];
    float ss = v.x * v.x + v.y * v.y + v.z * v.z + v.w * v.w;
    #pragma unroll
    for (int off = 32; off; off >>= 1) ss += __shfl_xor(ss, off, 64);
    const float rn = 1.0f / sqrtf(ss);
    ushort4 o;
    o.x = f2bf(v.x * rn); o.y = f2bf(v.y * rn);
    o.z = f2bf(v.z * rn); o.w = f2bf(v.w * rn);
    ((ushort4*)(out + (size_t)row * 256))[lane] = o;
}

// ---------------------------------------------------------------- MFMA attention
// out_fm[b][d][q] = sum_k relu(qn[b,q,:].kn[b,k,:]) * ow[b,k] * vT[b,d,k]
// grid 512 = b(4) x dhalf(2) x qtile(64); block 256 (4 waves).
// Wave (qg,kg): QK computes S[32q x 32k]; PV computes O[32q x 64d] (dg=kg).
__global__ __launch_bounds__(256, 2) void k_attn_mfma(
    const ushort* __restrict__ qn, const ushort* __restrict__ kn,
    const ushort* __restrict__ vpT, const float* __restrict__ ow,
    float* __restrict__ out_fm)
{
    __shared__ __align__(16) char smem[33280];   // P-tile (8KB) / epilogue tr (33280B)
    const int t  = threadIdx.x;
    const int w  = t >> 6, l = t & 63;
    const int lr = l & 31, lh = l >> 5;
    const int qg = w >> 1, kg = w & 1;           // PV d-group dg == kg
    const int bid = blockIdx.x;
    const int b = bid >> 7, dh = (bid >> 6) & 1, qb = bid & 63;
    const int q0 = qb << 6;
    const int dbase = dh << 7;

    // Q fragments for this wave's 32 q-rows (held in regs, 64 VGPR)
    const ushort* qrow = qn + ((size_t)b * kNQ + q0 + 32 * qg + lr) * kD + lh * 8;
    bf16x8 qf[16];
    #pragma unroll
    for (int ks = 0; ks < 16; ++ks) qf[ks] = *(const bf16x8*)(qrow + ks * 16);

    f32x16 o0{}, o1{};
    const float* owb = ow + b * kNK;
    for (int kt = 0; kt < 64; ++kt) {
        const int k0 = kt << 6;
        const float wsc = owb[k0 + 32 * kg + lr];
        // ---- QK^T : S[32q][32k], K-frags straight from global (L2-resident)
        const ushort* krow = kn + ((size_t)b * kNK + k0 + 32 * kg + lr) * kD + lh * 8;
        f32x16 s{};
        #pragma unroll
        for (int ks = 0; ks < 16; ++ks) {
            bf16x8 kf = *(const bf16x8*)(krow + ks * 16);
            s = __builtin_amdgcn_mfma_f32_32x32x16_bf16(qf[ks], kf, s, 0, 0, 0);
        }
        __syncthreads();   // prev PV done reading P
        // ---- P = relu(S)*w -> bf16 -> LDS (XOR-swizzled rows)
        {
            const int colb = (32 * kg + lr) << 1;
            #pragma unroll
            for (int r = 0; r < 16; ++r) {
                const int row = 32 * qg + (r & 3) + 8 * (r >> 2) + 4 * lh;
                int off = (row << 7) + colb;
                off ^= (row & 7) << 4;
                *(ushort*)(smem + off) = f2bf(fmaxf(s[r], 0.f) * wsc);
            }
        }
        __syncthreads();
        // ---- PV : O += P[32q][64k] * V[64k][64d], V^T-frags from global
        {
            const int prow = 32 * qg + lr;
            const int rsw  = (prow & 7) << 4;
            const ushort* vbase = vpT + ((size_t)b * kD + dbase + 64 * kg) * (size_t)kNK
                                + k0 + lh * 8;
            #pragma unroll
            for (int s4 = 0; s4 < 4; ++s4) {
                const int poff = (((prow << 7) + (s4 << 5) + (lh << 4)) ^ rsw);
                bf16x8 pf = *(const bf16x8*)(smem + poff);
                bf16x8 v0 = *(const bf16x8*)(vbase + (size_t)lr * kNK + s4 * 16);
                bf16x8 v1 = *(const bf16x8*)(vbase + (size_t)(32 + lr) * kNK + s4 * 16);
                o0 = __builtin_amdgcn_mfma_f32_32x32x16_bf16(pf, v0, o0, 0, 0, 0);
                o1 = __builtin_amdgcn_mfma_f32_32x32x16_bf16(pf, v1, o1, 0, 0, 0);
            }
        }
    }
    // ---- epilogue: transpose through LDS, coalesced [b][d][q] stores
    __syncthreads();
    float* tr = (float*)smem;   // [128][65]
    #pragma unroll
    for (int r = 0; r < 16; ++r) {
        const int ql = 32 * qg + (r & 3) + 8 * (r >> 2) + 4 * lh;
        const int d0 = 64 * kg + lr;
        tr[d0 * 65 + ql]        = o0[r];
        tr[(d0 + 32) * 65 + ql] = o1[r];
    }
    __syncthreads();
    float* ob = out_fm + ((size_t)b * kD + dbase) * (size_t)kHW + q0;
    #pragma unroll
    for (int j = 0; j < 32; ++j) {
        const int d = 4 * j + w, q = t & 63;
        ob[(size_t)d * kHW + q] = tr[d * 65 + q];
    }
}

// -------------------------------------------- conv3x3 (SAME) + BN + SiLU  (fp32)
__global__ __launch_bounds__(256) void k_conv3_bn_silu(
    const float* __restrict__ in, const float* __restrict__ cw,
    const float* __restrict__ bn_g, const float* __restrict__ bn_b,
    const float* __restrict__ bn_m, const float* __restrict__ bn_v,
    float* __restrict__ out)
{
    __shared__ float plane[4096];
    const int t   = threadIdx.x;
    const int b   = blockIdx.x >> 6;
    const int co0 = (blockIdx.x & 63) << 2;
    const int w   = t & 63;
    const int hb  = (t >> 6) << 4;
    const float* inb = in + (size_t)b * kD * kHW;
    float acc[4][16];
    #pragma unroll
    for (int c = 0; c < 4; ++c)
        #pragma unroll
        for (int j = 0; j < 16; ++j) acc[c][j] = 0.f;
    float4 pf[4];
    #pragma unroll
    for (int j = 0; j < 4; ++j)
        pf[j] = *(const float4*)&inb[(size_t)(t + 256 * j) * 4];
    for (int ci = 0; ci < 256; ++ci) {
        #pragma unroll
        for (int j = 0; j < 4; ++j)
            *(float4*)&plane[(t + 256 * j) * 4] = pf[j];
        __syncthreads();
        if (ci + 1 < 256) {
            #pragma unroll
            for (int j = 0; j < 4; ++j)
                pf[j] = *(const float4*)&inb[(size_t)(ci + 1) * kHW + (t + 256 * j) * 4];
        }
        float w9[4][9];
        #pragma unroll
        for (int c = 0; c < 4; ++c)
            #pragma unroll
            for (int k = 0; k < 9; ++k)
                w9[c][k] = cw[((size_t)(co0 + c) * 256 + ci) * 9 + k];
        float r00, r01, r02, r10, r11, r12, r20, r21, r22;
        if (hb > 0) {
            const float* row = &plane[(hb - 1) * 64];
            r00 = (w > 0) ? row[w - 1] : 0.f; r01 = row[w];
            r02 = (w < 63) ? row[w + 1] : 0.f;
        } else { r00 = r01 = r02 = 0.f; }
        {
            const float* row = &plane[hb * 64];
            r10 = (w > 0) ? row[w - 1] : 0.f; r11 = row[w];
            r12 = (w < 63) ? row[w + 1] : 0.f;
        }
        #pragma unroll
        for (int hh = 0; hh < 16; ++hh) {
            const int h2 = hb + hh + 1;
            if (h2 <= 63) {
                const float* row = &plane[h2 * 64];
                r20 = (w > 0) ? row[w - 1] : 0.f; r21 = row[w];
                r22 = (w < 63) ? row[w + 1] : 0.f;
            } else { r20 = r21 = r22 = 0.f; }
            #pragma unroll
            for (int c = 0; c < 4; ++c)
                acc[c][hh] += r00 * w9[c][0] + r01 * w9[c][1] + r02 * w9[c][2]
                            + r10 * w9[c][3] + r11 * w9[c][4] + r12 * w9[c][5]
                            + r20 * w9[c][6] + r21 * w9[c][7] + r22 * w9[c][8];
            r00 = r10; r01 = r11; r02 = r12;
            r10 = r20; r11 = r21; r12 = r22;
        }
        __syncthreads();
    }
    #pragma unroll
    for (int c = 0; c < 4; ++c) {
        const int co = co0 + c;
        const float inv = bn_g[co] / sqrtf(bn_v[co] + 1e-3f);
        const float add = bn_b[co] - bn_m[co] * inv;
        #pragma unroll
        for (int hh = 0; hh < 16; ++hh) {
            const float x = acc[c][hh] * inv + add;
            const float s = x / (1.f + expf(-x));
            out[((size_t)b * kD + co) * kHW + (hb + hh) * 64 + w] = s;
        }
    }
}

// ----------------------------------- conv1x1 + bias + residual (fp32)
__global__ __launch_bounds__(256) void k_conv1x1_res(
    const float* __restrict__ X, const float* __restrict__ W2,
    const float* __restrict__ bias2, const float* __restrict__ query,
    float* __restrict__ out)
{
    __shared__ float As[64][36];
    __shared__ float Xs[32][68];
    const int t   = threadIdx.x;
    const int b   = blockIdx.x >> 8;
    const int rem = blockIdx.x & 255;
    const int co0 = (rem >> 6) << 6;
    const int hw0 = (rem & 63) << 6;
    const int tx  = t & 15, ty = t >> 4;
    const float* Xb = X + (size_t)b * kD * kHW;
    float acc[4][4] = {};
    for (int kt = 0; kt < 8; ++kt) {
        const int k0 = kt * 32;
        {
            const int lr = t >> 3, lc = (t & 7) << 2;
            #pragma unroll
            for (int it = 0; it < 2; ++it) {
                const int r = lr + it * 32;
                *(float4*)&As[r][lc] =
                    *(const float4*)&W2[(size_t)(co0 + r) * 256 + k0 + lc];
            }
        }
        #pragma unroll
        for (int i = 0; i < 2; ++i) {
            const int idx = t + 256 * i;
            const int r = idx >> 4, c4 = (idx & 15) << 2;
            *(float4*)&Xs[r][c4] =
                *(const float4*)&Xb[(size_t)(k0 + r) * kHW + hw0 + c4];
        }
        __syncthreads();
        #pragma unroll
        for (int k4 = 0; k4 < 8; ++k4) {
            float4 a[4];
            #pragma unroll
            for (int i = 0; i < 4; ++i) a[i] = *(const float4*)&As[ty * 4 + i][k4 * 4];
            #pragma unroll
            for (int kk = 0; kk < 4; ++kk) {
                const float4 x = *(const float4*)&Xs[k4 * 4 + kk][tx * 4];
                #pragma unroll
                for (int i = 0; i < 4; ++i) {
                    const float av = ((const float*)&a[i])[kk];
                    acc[i][0] += av * x.x; acc[i][1] += av * x.y;
                    acc[i][2] += av * x.z; acc[i][3] += av * x.w;
                }
            }
        }
        __syncthreads();
    }
    #pragma unroll
    for (int i = 0; i < 4; ++i) {
        const int co = co0 + ty * 4 + i;
        const float bb = bias2[co];
        const size_t base = ((size_t)b * kD + co) * kHW + hw0 + tx * 4;
        const float4 q4 = *(const float4*)&query[base];
        float4 o;
        o.x = acc[i][0] + bb + q4.x; o.y = acc[i][1] + bb + q4.y;
        o.z = acc[i][2] + bb + q4.z; o.w = acc[i][3] + bb + q4.w;
        *(float4*)&out[base] = o;
    }
}

// ---------------------------------------------------------------- launch
extern "C" void kernel_launch(void* const* d_in, const int* in_sizes, int n_in,
                              void* d_out, int out_size, void* d_ws, size_t ws_size,
                              hipStream_t stream) {
    const float* query   = (const float*)d_in[0];
    const float* v_in    = (const float*)d_in[1];
    const float* qpos    = (const float*)d_in[2];
    const float* kpos    = (const float*)d_in[3];
    const float* otherW  = (const float*)d_in[4];
    const float* w_vs    = (const float*)d_in[5];
    const float* mlp_w1  = (const float*)d_in[6];
    const float* mlp_b1  = (const float*)d_in[7];
    const float* mlp_w2  = (const float*)d_in[8];
    const float* mlp_b2  = (const float*)d_in[9];
    const float* conv1_w = (const float*)d_in[10];
    const float* bn_g    = (const float*)d_in[11];
    const float* bn_b    = (const float*)d_in[12];
    const float* bn_m    = (const float*)d_in[13];
    const float* bn_v    = (const float*)d_in[14];
    const float* conv2_w = (const float*)d_in[15];
    const float* conv2_b = (const float*)d_in[16];
    float* out = (float*)d_out;
    float* ws  = (float*)d_ws;

    constexpr size_t M4 = 4194304;            // 4M floats = 16 MB
    float*  vproj = ws;                        // [B][NK][D] f32
    float*  qnf   = ws + M4;                   // [B][NQ][D] f32
    ushort* qn_bf = (ushort*)(ws + 2 * M4);    // [B][NQ][D] bf16
    ushort* kn_bf = (ushort*)(ws + 2 * M4 + M4 / 2);
    ushort* vpT   = (ushort*)(ws + 3 * M4);    // [B][D][NK] bf16
    float*  w1e   = ws + 3 * M4 + M4 / 2;
    float*  qhid    = out;                     // d_out as scratch
    float*  attn_fm = out;
    float*  silu    = vproj;                   // free after attention

    k_fold_w1<<<256, 256, 0, stream>>>(mlp_w1, w1e);
    k_gemm_awt<<<1024, 256, 0, stream>>>(v_in, w_vs, nullptr, vproj, 0);
    k_transpose_cvt<<<1024, 256, 0, stream>>>(vproj, vpT);
    k_gemm_awt<<<1024, 256, 0, stream>>>(qpos, w1e, mlp_b1, qhid, 1);
    k_gemm_awt<<<1024, 256, 0, stream>>>(qhid, mlp_w2, mlp_b2, qnf, 0);
    k_l2norm_bf16<<<4096, 256, 0, stream>>>(qnf, qn_bf);
    k_l2norm_bf16<<<4096, 256, 0, stream>>>(kpos, kn_bf);
    k_attn_mfma<<<512, 256, 0, stream>>>(qn_bf, kn_bf, vpT, otherW, attn_fm);
    k_conv3_bn_silu<<<256, 256, 0, stream>>>(attn_fm, conv1_w, bn_g, bn_b, bn_m, bn_v, silu);
    k_conv1x1_res<<<1024, 256, 0, stream>>>(silu, conv2_w, conv2_b, query, out);
}

// Round 5
// 570.057 us; speedup vs baseline: 3.7476x; 2.1065x over previous
//
#include <hip/hip_runtime.h>
#include <math.h>

// Fixed problem dims
constexpr int kB  = 4;
constexpr int kD  = 256;
constexpr int kNQ = 4096;
constexpr int kNK = 4096;
constexpr int kHW = 4096;   // 64*64

typedef __bf16 bf16x8 __attribute__((ext_vector_type(8)));
typedef float  f32x16 __attribute__((ext_vector_type(16)));

__device__ __forceinline__ unsigned short f2bf(float x) {
    unsigned int u = __builtin_bit_cast(unsigned int, x);
    u = (u + 0x7fffu + ((u >> 16) & 1u)) >> 16;
    return (unsigned short)u;
}

// ------------------------------------------------------------- f32 -> bf16
__global__ __launch_bounds__(256) void k_cvt_bf16(const float* __restrict__ in,
                                                  ushort* __restrict__ out) {
    const int i = blockIdx.x * 256 + threadIdx.x;   // one float4 each
    float4 v = ((const float4*)in)[i];
    ushort4 o;
    o.x = f2bf(v.x); o.y = f2bf(v.y); o.z = f2bf(v.z); o.w = f2bf(v.w);
    ((ushort4*)out)[i] = o;
}

// ---------------------------------------------------------------- fold w1 -> bf16
__global__ void k_fold_w1(const float* __restrict__ w1, ushort* __restrict__ w1e) {
    int h = blockIdx.x, d = threadIdx.x;
    w1e[h * 256 + d] = f2bf(w1[h * 512 + d] + w1[h * 512 + 256 + d]);
}

// ------------------------------------------- conv1 weights -> bf16 [9][co][ci]
__global__ void k_repack_w9(const float* __restrict__ cw, ushort* __restrict__ w9) {
    const int ci = threadIdx.x;
    const int co = blockIdx.x & 255;
    const int s  = blockIdx.x >> 8;     // grid 9*256
    w9[((size_t)s * 256 + co) * 256 + ci] = f2bf(cw[((size_t)co * 256 + ci) * 9 + s]);
}

// ----------------------------------------------- generic MFMA GEMM  C = A @ W^T
// A [M,256] bf16, W [256,256] bf16 ([n][k]). Block: 128m x 64n, 4 waves (2x2).
// EPI: 0 = f32 [m][256]; 1 = bf16 [m][256]; 2 = bf16 transposed per-batch [b][n][4096]
template<int EPI, int RELU>
__global__ __launch_bounds__(256, 2) void k_gemm_mfma(
    const ushort* __restrict__ A, const ushort* __restrict__ W,
    const float* __restrict__ bias, void* __restrict__ outp)
{
    const int t = threadIdx.x, w = t >> 6, l = t & 63, lr = l & 31, lh = l >> 5;
    const int m0 = (blockIdx.x >> 2) * 128;
    const int n0 = (blockIdx.x & 3) * 64;
    const int wm = w >> 1, wn = w & 1;
    const ushort* Ar0 = A + (size_t)(m0 + wm * 64 + lr) * 256 + lh * 8;
    const ushort* Ar1 = Ar0 + 32 * 256;
    const ushort* Wr  = W + (size_t)(n0 + wn * 32 + lr) * 256 + lh * 8;
    f32x16 c0{}, c1{};
    #pragma unroll
    for (int ks = 0; ks < 16; ++ks) {
        bf16x8 a0 = *(const bf16x8*)(Ar0 + ks * 16);
        bf16x8 a1 = *(const bf16x8*)(Ar1 + ks * 16);
        bf16x8 wf = *(const bf16x8*)(Wr + ks * 16);
        c0 = __builtin_amdgcn_mfma_f32_32x32x16_bf16(a0, wf, c0, 0, 0, 0);
        c1 = __builtin_amdgcn_mfma_f32_32x32x16_bf16(a1, wf, c1, 0, 0, 0);
    }
    const int n = n0 + wn * 32 + lr;            // C col for both accs
    float bb = bias ? bias[n] : 0.f;
    if constexpr (EPI == 2) {
        __shared__ ushort tr[64][136];          // [n_local][m_local], 16B-aligned rows
        #pragma unroll
        for (int r = 0; r < 16; ++r) {
            const int ml = wm * 64 + (r & 3) + 8 * (r >> 2) + 4 * lh;
            float v0 = c0[r], v1 = c1[r];
            if (RELU) { v0 = fmaxf(v0, 0.f); v1 = fmaxf(v1, 0.f); }
            tr[wn * 32 + lr][ml]      = f2bf(v0);
            tr[wn * 32 + lr][ml + 32] = f2bf(v1);
        }
        __syncthreads();
        ushort* out = (ushort*)outp;
        const int b = m0 >> 12, mm = m0 & 4095;
        const int row = t >> 2, seg = t & 3;    // 64 rows x 4 segs of 32 cols
        uint4 u0 = *(uint4*)&tr[row][seg * 32];
        uint4 u1 = *(uint4*)&tr[row][seg * 32 + 8];
        uint4 u2 = *(uint4*)&tr[row][seg * 32 + 16];
        uint4 u3 = *(uint4*)&tr[row][seg * 32 + 24];
        ushort* ob = out + ((size_t)b * 256 + n0 + row) * 4096 + mm + seg * 32;
        *(uint4*)ob        = u0; *(uint4*)(ob + 8)  = u1;
        *(uint4*)(ob + 16) = u2; *(uint4*)(ob + 24) = u3;
    } else {
        #pragma unroll
        for (int r = 0; r < 16; ++r) {
            const int m = m0 + wm * 64 + (r & 3) + 8 * (r >> 2) + 4 * lh;
            float v0 = c0[r] + bb, v1 = c1[r] + bb;
            if (RELU) { v0 = fmaxf(v0, 0.f); v1 = fmaxf(v1, 0.f); }
            if constexpr (EPI == 0) {
                float* out = (float*)outp;
                out[(size_t)m * 256 + n]      = v0;
                out[(size_t)(m + 32) * 256 + n] = v1;
            } else {
                ushort* out = (ushort*)outp;
                out[(size_t)m * 256 + n]      = f2bf(v0);
                out[(size_t)(m + 32) * 256 + n] = f2bf(v1);
            }
        }
    }
}

// ---------------------------------------------------------------- L2 norm -> bf16
__global__ __launch_bounds__(256) void k_l2norm_bf16(const float* __restrict__ in,
                                                     ushort* __restrict__ out) {
    const int row  = blockIdx.x * 4 + (threadIdx.x >> 6);
    const int lane = threadIdx.x & 63;
    float4 v = ((const float4*)(in + (size_t)row * 256))[lane];
    float ss = v.x * v.x + v.y * v.y + v.z * v.z + v.w * v.w;
    #pragma unroll
    for (int off = 32; off; off >>= 1) ss += __shfl_xor(ss, off, 64);
    const float rn = 1.0f / sqrtf(ss);
    ushort4 o;
    o.x = f2bf(v.x * rn); o.y = f2bf(v.y * rn);
    o.z = f2bf(v.z * rn); o.w = f2bf(v.w * rn);
    ((ushort4*)(out + (size_t)row * 256))[lane] = o;
}

// ---------------------------------------------------------------- MFMA attention
// X[b][q][d] (bf16 out) = sum_k relu(qn[b,q,:].kn[b,k,:]) * ow[b,k] * vT[b,d,k]
// grid 512 = b(4) x dhalf(2) x qtile(64); block 256 (4 waves).
__global__ __launch_bounds__(256, 2) void k_attn_mfma(
    const ushort* __restrict__ qn, const ushort* __restrict__ kn,
    const ushort* __restrict__ vpT, const float* __restrict__ ow,
    ushort* __restrict__ X)
{
    __shared__ __align__(16) char smem[8192];    // P tile, XOR-swizzled
    const int t  = threadIdx.x;
    const int w  = t >> 6, l = t & 63;
    const int lr = l & 31, lh = l >> 5;
    const int qg = w >> 1, kg = w & 1;
    const int bid = blockIdx.x;
    const int b = bid >> 7, dh = (bid >> 6) & 1, qb = bid & 63;
    const int q0 = qb << 6;
    const int dbase = dh << 7;

    const ushort* qrow = qn + ((size_t)b * kNQ + q0 + 32 * qg + lr) * kD + lh * 8;
    bf16x8 qf[16];
    #pragma unroll
    for (int ks = 0; ks < 16; ++ks) qf[ks] = *(const bf16x8*)(qrow + ks * 16);

    f32x16 o0{}, o1{};
    const float* owb = ow + b * kNK;
    for (int kt = 0; kt < 64; ++kt) {
        const int k0 = kt << 6;
        const float wsc = owb[k0 + 32 * kg + lr];
        const ushort* krow = kn + ((size_t)b * kNK + k0 + 32 * kg + lr) * kD + lh * 8;
        f32x16 s{};
        #pragma unroll
        for (int ks = 0; ks < 16; ++ks) {
            bf16x8 kf = *(const bf16x8*)(krow + ks * 16);
            s = __builtin_amdgcn_mfma_f32_32x32x16_bf16(qf[ks], kf, s, 0, 0, 0);
        }
        __syncthreads();
        {
            const int colb = (32 * kg + lr) << 1;
            #pragma unroll
            for (int r = 0; r < 16; ++r) {
                const int row = 32 * qg + (r & 3) + 8 * (r >> 2) + 4 * lh;
                int off = (row << 7) + colb;
                off ^= (row & 7) << 4;
                *(ushort*)(smem + off) = f2bf(fmaxf(s[r], 0.f) * wsc);
            }
        }
        __syncthreads();
        {
            const int prow = 32 * qg + lr;
            const int rsw  = (prow & 7) << 4;
            const ushort* vbase = vpT + ((size_t)b * kD + dbase + 64 * kg) * (size_t)kNK
                                + k0 + lh * 8;
            #pragma unroll
            for (int s4 = 0; s4 < 4; ++s4) {
                const int poff = (((prow << 7) + (s4 << 5) + (lh << 4)) ^ rsw);
                bf16x8 pf = *(const bf16x8*)(smem + poff);
                bf16x8 v0 = *(const bf16x8*)(vbase + (size_t)lr * kNK + s4 * 16);
                bf16x8 v1 = *(const bf16x8*)(vbase + (size_t)(32 + lr) * kNK + s4 * 16);
                o0 = __builtin_amdgcn_mfma_f32_32x32x16_bf16(pf, v0, o0, 0, 0, 0);
                o1 = __builtin_amdgcn_mfma_f32_32x32x16_bf16(pf, v1, o1, 0, 0, 0);
            }
        }
    }
    // epilogue: bf16 X[b][q][d] direct (channel-last for the convs)
    const int dA = dbase + 64 * kg + lr;
    ushort* Xo = X + ((size_t)b * kNQ + q0) * 256;
    #pragma unroll
    for (int r = 0; r < 16; ++r) {
        const int q = 32 * qg + (r & 3) + 8 * (r >> 2) + 4 * lh;
        Xo[(size_t)q * 256 + dA]      = f2bf(o0[r]);
        Xo[(size_t)q * 256 + dA + 32] = f2bf(o1[r]);
    }
}

// ------------------------------- conv3x3 + BN + SiLU as 9 shifted MFMA GEMMs
// X [b][p][ci] bf16 -> Y [b][p][co] bf16. Block: 64co x 128p, 4 waves (2x2).
__global__ __launch_bounds__(256, 2) void k_conv3_mfma(
    const ushort* __restrict__ X, const ushort* __restrict__ W9,
    const float* __restrict__ bn_g, const float* __restrict__ bn_b,
    const float* __restrict__ bn_m, const float* __restrict__ bn_v,
    ushort* __restrict__ Y)
{
    __shared__ float binv[256], badd[256];
    __shared__ ushort tr[128][72];               // [p_local][co_local], 144B rows
    const int t = threadIdx.x, w = t >> 6, l = t & 63, lr = l & 31, lh = l >> 5;
    {
        float inv = bn_g[t] * rsqrtf(bn_v[t] + 1e-3f);
        binv[t] = inv;
        badd[t] = bn_b[t] - bn_m[t] * inv;
    }
    __syncthreads();
    const int bid = blockIdx.x;                  // 4b x 4co x 32p
    const int b = bid >> 7, ct = (bid >> 5) & 3, pt = bid & 31;
    const int co0 = ct * 64, p0 = pt * 128;
    const int wc = w >> 1, wp = w & 1;
    const int h0 = (p0 >> 6) + wp;               // uniform h for this wave
    const int pA = p0 + wp * 64 + lr;            // w_ = lr (sub A), +32 (sub B)
    const ushort* Xb = X + (size_t)b * 4096 * 256;
    const ushort* Wbase = W9 + (size_t)(co0 + wc * 32 + lr) * 256 + lh * 8;
    const bf16x8 bz = {};
    f32x16 o0{}, o1{};
    for (int dy = -1; dy <= 1; ++dy) {
        const int hh = h0 + dy;
        if (hh < 0 || hh > 63) continue;
        for (int dx = -1; dx <= 1; ++dx) {
            const int s = (dy + 1) * 3 + (dx + 1);
            const bool invA = (dx == -1) && (lr == 0);
            const bool invB = (dx == 1) && (lr == 31);
            const ushort* pAp = Xb + (size_t)(pA + dy * 64 + dx) * 256 + lh * 8;
            const ushort* pBp = pAp + 32 * 256;
            const ushort* wr  = Wbase + (size_t)s * 65536;
            #pragma unroll
            for (int ks = 0; ks < 16; ++ks) {
                bf16x8 af = *(const bf16x8*)(wr + ks * 16);
                bf16x8 b0 = *(const bf16x8*)(pAp + ks * 16);
                bf16x8 b1 = *(const bf16x8*)(pBp + ks * 16);
                if (invA) b0 = bz;
                if (invB) b1 = bz;
                o0 = __builtin_amdgcn_mfma_f32_32x32x16_bf16(af, b0, o0, 0, 0, 0);
                o1 = __builtin_amdgcn_mfma_f32_32x32x16_bf16(af, b1, o1, 0, 0, 0);
            }
        }
    }
    // BN + SiLU -> bf16, transpose to [p][co] through LDS
    #pragma unroll
    for (int r = 0; r < 16; ++r) {
        const int co_l = wc * 32 + (r & 3) + 8 * (r >> 2) + 4 * lh;
        const int co = co0 + co_l;
        const float inv = binv[co], add = badd[co];
        float x0 = o0[r] * inv + add;
        float x1 = o1[r] * inv + add;
        x0 = x0 / (1.f + expf(-x0));
        x1 = x1 / (1.f + expf(-x1));
        tr[wp * 64 + lr][co_l]      = f2bf(x0);
        tr[wp * 64 + 32 + lr][co_l] = f2bf(x1);
    }
    __syncthreads();
    // write-out: 128 rows x 64 cols; 256 threads x 32 ushorts = full tile
    const int pp = t >> 1, half = t & 1;
    uint4 u0 = *(uint4*)&tr[pp][half * 32];
    uint4 u1 = *(uint4*)&tr[pp][half * 32 + 8];
    uint4 u2 = *(uint4*)&tr[pp][half * 32 + 16];
    uint4 u3 = *(uint4*)&tr[pp][half * 32 + 24];
    ushort* yb = Y + ((size_t)b * 4096 + p0 + pp) * 256 + co0 + half * 32;
    *(uint4*)yb        = u0; *(uint4*)(yb + 8)  = u1;
    *(uint4*)(yb + 16) = u2; *(uint4*)(yb + 24) = u3;
}

// ------------------------- conv1x1 + bias + residual: out = q + Y @ W2^T + b2
// Y [b][p][ci] bf16, W2 [co][ci] bf16 -> out [b][co][p] f32 (coalesced stores)
__global__ __launch_bounds__(256, 2) void k_conv1x1_mfma(
    const ushort* __restrict__ Y, const ushort* __restrict__ W2,
    const float* __restrict__ bias2, const float* __restrict__ query,
    float* __restrict__ out)
{
    const int t = threadIdx.x, w = t >> 6, l = t & 63, lr = l & 31, lh = l >> 5;
    const int bid = blockIdx.x;                  // 4b x 4co x 32p
    const int b = bid >> 7, ct = (bid >> 5) & 3, pt = bid & 31;
    const int co0 = ct * 64, p0 = pt * 128;
    const int wc = w >> 1, wp = w & 1;
    const ushort* Wr = W2 + (size_t)(co0 + wc * 32 + lr) * 256 + lh * 8;
    const ushort* Yp = Y + ((size_t)b * 4096 + p0 + wp * 64 + lr) * 256 + lh * 8;
    f32x16 o0{}, o1{};
    #pragma unroll
    for (int ks = 0; ks < 16; ++ks) {
        bf16x8 wf = *(const bf16x8*)(Wr + ks * 16);
        bf16x8 y0 = *(const bf16x8*)(Yp + ks * 16);
        bf16x8 y1 = *(const bf16x8*)(Yp + 32 * 256 + ks * 16);
        o0 = __builtin_amdgcn_mfma_f32_32x32x16_bf16(wf, y0, o0, 0, 0, 0);
        o1 = __builtin_amdgcn_mfma_f32_32x32x16_bf16(wf, y1, o1, 0, 0, 0);
    }
    #pragma unroll
    for (int r = 0; r < 16; ++r) {
        const int co = co0 + wc * 32 + (r & 3) + 8 * (r >> 2) + 4 * lh;
        const float bb = bias2[co];
        const size_t base = ((size_t)b * 256 + co) * 4096 + p0 + wp * 64 + lr;
        out[base]      = o0[r] + bb + query[base];
        out[base + 32] = o1[r] + bb + query[base + 32];
    }
}

// ---------------------------------------------------------------- launch
extern "C" void kernel_launch(void* const* d_in, const int* in_sizes, int n_in,
                              void* d_out, int out_size, void* d_ws, size_t ws_size,
                              hipStream_t stream) {
    const float* query   = (const float*)d_in[0];
    const float* v_in    = (const float*)d_in[1];
    const float* qpos    = (const float*)d_in[2];
    const float* kpos    = (const float*)d_in[3];
    const float* otherW  = (const float*)d_in[4];
    const float* w_vs    = (const float*)d_in[5];
    const float* mlp_w1  = (const float*)d_in[6];
    const float* mlp_b1  = (const float*)d_in[7];
    const float* mlp_w2  = (const float*)d_in[8];
    const float* mlp_b2  = (const float*)d_in[9];
    const float* conv1_w = (const float*)d_in[10];
    const float* bn_g    = (const float*)d_in[11];
    const float* bn_b    = (const float*)d_in[12];
    const float* bn_m    = (const float*)d_in[13];
    const float* bn_v    = (const float*)d_in[14];
    const float* conv2_w = (const float*)d_in[15];
    const float* conv2_b = (const float*)d_in[16];
    float* out = (float*)d_out;
    char* base = (char*)d_ws;

    constexpr size_t MB = 1u << 20;
    ushort* v_bf    = (ushort*)(base);             // 8MB   (dead after vproj)
    ushort* qpos_bf = (ushort*)(base + 8 * MB);    // 8MB   (dead after mlp1)
    float*  qp_f32  = (float*) (base);             // 16MB  (aliases v_bf+qpos_bf)
    ushort* qhid_bf = (ushort*)(base + 16 * MB);   // 8MB   (dead after mlp2)
    ushort* X_bf    = (ushort*)(base + 16 * MB);   // 8MB   (attn out, aliases qhid)
    ushort* qn_bf   = (ushort*)(base + 24 * MB);   // 8MB   (dead after attn)
    ushort* Y_bf    = (ushort*)(base + 24 * MB);   // 8MB   (conv3 out, aliases qn)
    ushort* kn_bf   = (ushort*)(base + 32 * MB);   // 8MB
    ushort* vT_bf   = (ushort*)(base + 40 * MB);   // 8MB
    ushort* wvs_bf  = (ushort*)(base + 48 * MB);
    ushort* w1e_bf  = (ushort*)(base + 48 * MB + 128 * 1024);
    ushort* w2_bf   = (ushort*)(base + 48 * MB + 256 * 1024);
    ushort* c2_bf   = (ushort*)(base + 48 * MB + 384 * 1024);
    ushort* w9_bf   = (ushort*)(base + 48 * MB + 512 * 1024);   // 1.125MB

    k_cvt_bf16<<<4096, 256, 0, stream>>>(v_in, v_bf);
    k_cvt_bf16<<<64, 256, 0, stream>>>(w_vs, wvs_bf);
    k_cvt_bf16<<<64, 256, 0, stream>>>(mlp_w2, w2_bf);
    k_cvt_bf16<<<64, 256, 0, stream>>>(conv2_w, c2_bf);
    k_fold_w1<<<256, 256, 0, stream>>>(mlp_w1, w1e_bf);
    k_repack_w9<<<2304, 256, 0, stream>>>(conv1_w, w9_bf);
    k_cvt_bf16<<<4096, 256, 0, stream>>>(qpos, qpos_bf);

    k_gemm_mfma<2, 0><<<512, 256, 0, stream>>>(v_bf, wvs_bf, nullptr, vT_bf);
    k_gemm_mfma<1, 1><<<512, 256, 0, stream>>>(qpos_bf, w1e_bf, mlp_b1, qhid_bf);
    k_gemm_mfma<0, 0><<<512, 256, 0, stream>>>(qhid_bf, w2_bf, mlp_b2, qp_f32);
    k_l2norm_bf16<<<4096, 256, 0, stream>>>(qp_f32, qn_bf);
    k_l2norm_bf16<<<4096, 256, 0, stream>>>(kpos, kn_bf);
    k_attn_mfma<<<512, 256, 0, stream>>>(qn_bf, kn_bf, vT_bf, otherW, X_bf);
    k_conv3_mfma<<<512, 256, 0, stream>>>(X_bf, w9_bf, bn_g, bn_b, bn_m, bn_v, Y_bf);
    k_conv1x1_mfma<<<512, 256, 0, stream>>>(Y_bf, c2_bf, conv2_b, query, out);
}